// Round 8
// baseline (244.728 us; speedup 1.0000x reference)
//
#include <hip/hip_runtime.h>
#include <math.h>

#define S_LEN 8192
#define DHEAD 64
#define NBATCH 4
#define BK 32
#define KIT 64            // 2048 keys per kq-quarter / BK

typedef unsigned short u16;
typedef unsigned int u32;
typedef __attribute__((ext_vector_type(8))) _Float16 half8;
typedef __attribute__((ext_vector_type(2))) __fp16 fp16x2;
typedef __attribute__((ext_vector_type(4))) float f32x4;

union HU8 { int4 i4; half8 h8; u32 w[4]; };
union H2U { fp16x2 h2; u32 w; };
union HU  { _Float16 h; u16 u; };

#if __has_builtin(__builtin_amdgcn_exp2f)
#define EXP2(x) __builtin_amdgcn_exp2f(x)
#else
#define EXP2(x) exp2f(x)
#endif

// float -> f16 RNE
__device__ __forceinline__ u16 f2h(float f) {
    HU x; x.h = (_Float16)f; return x.u;
}
// two floats -> packed f16x2, single v_cvt_pkrtz_f16_f32
__device__ __forceinline__ u32 packh2(float a, float b) {
    H2U x; x.h2 = __builtin_amdgcn_cvt_pkrtz(a, b); return x.w;
}

// ---------------------------------------------------------------------------
// Prep: blocks [0,1024) pack K and V (both f16) of one 32-key tile
// (b = bid>>8, t = bid&255) into MFMA-fragment order:
//   blob[b][t] (8 KB) = K chunks j=0..3 (j=kt*2+ds) then V chunks dt=0..3,
//   chunk = 64 lanes x 16 B, exact flash lane order:
//     K: lane(low,h) -> K[b][t*32 + 8*(low>>2)+4*kt+(low&3)][ds*32+h*8+0..7]
//     V: lane(low,h) -> V[b][t*32 + h*8 + 0..7][dt*16+low]
// Blocks [1024,1056): Julia bias in f64 (matches numpy), fixed max M=20
// folded: bias2[k] = log(exp(et*scale)+1e-8)*log2e - 20.
// ---------------------------------------------------------------------------
__global__ void prep_kernel(const float* __restrict__ K, const float* __restrict__ V,
                            const float* crp, const float* cip, const float* scp,
                            u16* __restrict__ blob, float* __restrict__ bias2) {
    int bid = blockIdx.x, tid = threadIdx.x;
    if (bid < 1024) {
        int b = bid >> 8, t = bid & 255;
        __shared__ float Kt[32 * 64];
        __shared__ float Vt[32 * 65];          // padded rows: conflict-free col reads
        int row = tid >> 3, c8 = (tid & 7) * 8;
        const float* ks = K + ((size_t)(b * S_LEN + t * 32 + row)) * 64 + c8;
        const float* vs = V + ((size_t)(b * S_LEN + t * 32 + row)) * 64 + c8;
        float4 ka = *(const float4*)ks, kb4 = *(const float4*)(ks + 4);
        float4 va = *(const float4*)vs, vb4 = *(const float4*)(vs + 4);
        *(float4*)&Kt[row * 64 + c8] = ka;
        *(float4*)&Kt[row * 64 + c8 + 4] = kb4;
        float* vr = &Vt[row * 65 + c8];
        vr[0] = va.x; vr[1] = va.y; vr[2] = va.z; vr[3] = va.w;
        vr[4] = vb4.x; vr[5] = vb4.y; vr[6] = vb4.z; vr[7] = vb4.w;
        __syncthreads();

        int j = tid >> 6, lane = tid & 63, low = lane & 15, h = lane >> 4;
        u16* tb = blob + ((size_t)(b * 256 + t)) * 4096;   // u16 elems (8 KB)
        {   // K chunk j = kt*2 + ds  (f16)
            int kt = j >> 1, ds = j & 1;
            int krow = 8 * (low >> 2) + 4 * kt + (low & 3);
            const float* src = &Kt[krow * 64 + ds * 32 + h * 8];
            u32 wds[4];
#pragma unroll
            for (int i = 0; i < 4; ++i)
                wds[i] = (u32)f2h(src[2 * i]) | ((u32)f2h(src[2 * i + 1]) << 16);
            *(int4*)(tb + j * 512 + lane * 8) = make_int4(wds[0], wds[1], wds[2], wds[3]);
        }
        {   // V chunk dt = j  (f16)
            int col = j * 16 + low;
            u32 wds[4];
#pragma unroll
            for (int i = 0; i < 4; ++i) {
                float a = Vt[(h * 8 + 2 * i) * 65 + col];
                float c = Vt[(h * 8 + 2 * i + 1) * 65 + col];
                wds[i] = (u32)f2h(a) | ((u32)f2h(c) << 16);
            }
            *(int4*)(tb + 2048 + j * 512 + lane * 8) = make_int4(wds[0], wds[1], wds[2], wds[3]);
        }
    } else {
#pragma clang fp contract(off)
        int i = (bid - 1024) * 256 + tid;
        double cr = (double)crp[0], ci = (double)cip[0], sc = (double)scp[0];
        double step = 4.0 / (double)(S_LEN - 1);
        double x = (i == S_LEN - 1) ? 2.0 : (-2.0 + step * (double)i);
        double zr = x, zi = 0.0, et = 1.0;
        bool esc = false;
        for (int it = 0; it < 64; ++it) {
            double nzr = zr * zr - zi * zi + cr;
            double nzi = 2.0 * zr * zi + ci;
            if (!esc) { zr = nzr; zi = nzi; }
            double m2 = zr * zr + zi * zi;
            if (!esc && m2 > 4.0) { et = (double)it / 64.0; esc = true; }
        }
        double bias = log(exp(et * sc) + 1e-8);
        bias2[i] = (float)(bias * 1.4426950408889634 - 20.0);
    }
}

// ---------------------------------------------------------------------------
// Flash: packed-fragment streaming, no LDS / no barriers in the main loop.
//   grid 512 (2 blocks/CU), block 256 = 4 waves = 4 kq; each wave covers the
//   block's 64 q-rows (4 q-frags) x its 2048-key quarter, BK=32, 64 iters.
//
//   PIPE-INTERLEAVED PIPELINE (this revision).  R7 counters: VALU port needs
//   ~633 cyc/wave-iter, matrix pipe ~563, measured iter ~1400 = their SUM --
//   the phases were emitted as blocks (16 MFMA / 150 VALU / 16 MFMA), so a
//   wave can never issue VALU while stalled on back-to-back MFMAs, and the
//   2 lockstepped waves/SIMD don't rescue it.  Perfect overlap = max(633,
//   563) x 128 wave-iters ~ 34-40 us.  New body:
//     Phase A (x4, per qf): the 4 QK(i) MFMAs for this qf (2 independent
//       chains) issued alongside SM(i-1) for the SAME qf (reads stPrev, one
//       iter old -> no dependency on the in-flight QK).  Ready VALU sits
//       between MFMAs in one dependency-free window -> list scheduler can
//       interleave; matrix pipe runs QK while VALU chews exp2/pack.
//     Phase B: PV(i-1) (16 MFMA, operands ready), wrapped in s_setprio(1/0)
//       (T5): the MFMA-entering wave wins arbitration -> wave pair drifts
//       into anti-phase, PV overlaps the other wave's Phase A VALU.
//   st lives across the loop boundary -> stA/stB named buffers, explicit
//   odd/even bodies (compile-time indices only).  launch_bounds(256,2) is
//   the only known-good occupancy setting (R2/R3/R6 all spilled under
//   tighter caps; R5 proved buying occupancy with shape loses).
//
//   All operands f16; fixed-max softmax (M=20 folded into bias);
//   4-way split-K merged by plain adds through LDS at the end.
// ---------------------------------------------------------------------------
__global__ __launch_bounds__(256, 2)
void flash_kernel(const float* __restrict__ Q, const u16* __restrict__ blob,
                  const float* __restrict__ bias2, float* __restrict__ Out) {
    __shared__ __align__(16) char smem[17664];   // merge scratch only

    const int tid = threadIdx.x;
    const int l = tid & 63, low = l & 15, h = l >> 4;
    const int kq = __builtin_amdgcn_readfirstlane(tid >> 6);

    const int bid = blockIdx.x;
    const int batch = bid & 3;          // XCD-affinity: batch b on XCDs {b, b+4}
    const int qtile = bid >> 2;         // 0..127 (BQ = 64)
    const int q0 = qtile * 64;

    // ---- Q fragments (4 x 16 q-rows, f16), scale log2(e)/8 folded ----
    const float qscale = 0.18033688011112042f;
    half8 qfrag[4][2];
#pragma unroll
    for (int qf = 0; qf < 4; ++qf) {
        const float* qrow = Q + ((size_t)(batch * S_LEN + q0 + qf * 16 + low)) * DHEAD + h * 8;
#pragma unroll
        for (int ds = 0; ds < 2; ++ds) {
            f32x4 a = *(const f32x4*)(qrow + ds * 32);
            f32x4 b = *(const f32x4*)(qrow + ds * 32 + 4);
            HU8 u;
            u.w[0] = packh2(a[0] * qscale, a[1] * qscale);
            u.w[1] = packh2(a[2] * qscale, a[3] * qscale);
            u.w[2] = packh2(b[0] * qscale, b[1] * qscale);
            u.w[3] = packh2(b[2] * qscale, b[3] * qscale);
            qfrag[qf][ds] = u.h8;
        }
    }

    // wave-uniform stream base (SGPR) + single lane offset (VGPR)
    const u16* kvb = blob + ((size_t)(batch * 256 + kq * 64)) * 4096;
    const int loff = l * 8;                         // u16 elems (16 B/lane)
    const float* bbase = bias2 + kq * 2048;

    f32x4 o[4][4];
#pragma unroll
    for (int qf = 0; qf < 4; ++qf)
#pragma unroll
        for (int dt = 0; dt < 4; ++dt) o[qf][dt] = (f32x4){0, 0, 0, 0};
    float lsum[4] = {0.f, 0.f, 0.f, 0.f};

    HU8 kf[4];           // K buffer (compiler renames across WAR)
    f32x4 bvv[2];        // bias buffer
    HU8 vf[4];           // V buffer
    HU8 pf[4];           // P frags (SM output, PV input)
    f32x4 stA[2][4];     // score buffers: st(i) lives until SM in iter i+1
    f32x4 stB[2][4];

    // ---- prologue: QK(0) -> stA; issue K/bias(1), V(0) ----
#pragma unroll
    for (int j = 0; j < 4; ++j) kf[j].i4 = *(const int4*)(kvb + j * 512 + loff);
    bvv[0] = *(const f32x4*)(bbase + h * 8);
    bvv[1] = *(const f32x4*)(bbase + h * 8 + 4);
#pragma unroll
    for (int kt = 0; kt < 2; ++kt) {
        const f32x4 binit = kt ? bvv[1] : bvv[0];
#pragma unroll
        for (int qf = 0; qf < 4; ++qf) {
            f32x4 a = __builtin_amdgcn_mfma_f32_16x16x32_f16(kf[kt * 2].h8, qfrag[qf][0], binit, 0, 0, 0);
            a = __builtin_amdgcn_mfma_f32_16x16x32_f16(kf[kt * 2 + 1].h8, qfrag[qf][1], a, 0, 0, 0);
            stA[kt][qf] = a;
        }
    }
#pragma unroll
    for (int j = 0; j < 4; ++j) kf[j].i4 = *(const int4*)(kvb + 4096 + j * 512 + loff);
    bvv[0] = *(const f32x4*)(bbase + 32 + h * 8);
    bvv[1] = *(const f32x4*)(bbase + 32 + h * 8 + 4);
#pragma unroll
    for (int j = 0; j < 4; ++j) vf[j].i4 = *(const int4*)(kvb + 2048 + j * 512 + loff);

    // BODY(KI, STC, STP):
    //   Phase A per qf: QK(KI) chains (kt0: kf[0],kf[1]+bvv[0]; kt1:
    //     kf[2],kf[3]+bvv[1]) -> STC[*][qf], interleaved with SM(KI-1)
    //     from STP[*][qf] -> pf[qf], lsum
    //   then issue K/bias(KI+1)  (kf/bvv WAR -> compiler renames)
    //   Phase B: PV(KI-1) under setprio(1); then issue V(KI) -> vf
#define BODY(KI, STC, STP)                                                       \
    {                                                                            \
        const u16* tb_ = kvb + (size_t)(KI) * 4096;                              \
        const u16* tn_ = tb_ + 4096;                                             \
        _Pragma("unroll")                                                        \
        for (int qf = 0; qf < 4; ++qf) {                                         \
            f32x4 a0 = __builtin_amdgcn_mfma_f32_16x16x32_f16(                   \
                kf[0].h8, qfrag[qf][0], bvv[0], 0, 0, 0);                        \
            f32x4 a1 = __builtin_amdgcn_mfma_f32_16x16x32_f16(                   \
                kf[2].h8, qfrag[qf][0], bvv[1], 0, 0, 0);                        \
            float p0 = EXP2(STP[0][qf][0]), p1 = EXP2(STP[0][qf][1]);            \
            float p2 = EXP2(STP[0][qf][2]), p3 = EXP2(STP[0][qf][3]);            \
            float p4 = EXP2(STP[1][qf][0]), p5 = EXP2(STP[1][qf][1]);            \
            float p6 = EXP2(STP[1][qf][2]), p7 = EXP2(STP[1][qf][3]);            \
            STC[0][qf] = __builtin_amdgcn_mfma_f32_16x16x32_f16(                 \
                kf[1].h8, qfrag[qf][1], a0, 0, 0, 0);                            \
            STC[1][qf] = __builtin_amdgcn_mfma_f32_16x16x32_f16(                 \
                kf[3].h8, qfrag[qf][1], a1, 0, 0, 0);                            \
            lsum[qf] += ((p0 + p1) + (p2 + p3)) + ((p4 + p5) + (p6 + p7));       \
            pf[qf].w[0] = packh2(p0, p1);                                        \
            pf[qf].w[1] = packh2(p2, p3);                                        \
            pf[qf].w[2] = packh2(p4, p5);                                        \
            pf[qf].w[3] = packh2(p6, p7);                                        \
        }                                                                        \
        _Pragma("unroll")                                                        \
        for (int j = 0; j < 4; ++j)                                              \
            kf[j].i4 = *(const int4*)(tn_ + j * 512 + loff);                     \
        const float* bpn_ = bbase + ((KI) + 1) * 32 + h * 8;                     \
        bvv[0] = *(const f32x4*)bpn_;                                            \
        bvv[1] = *(const f32x4*)(bpn_ + 4);                                      \
        __builtin_amdgcn_s_setprio(1);                                           \
        _Pragma("unroll")                                                        \
        for (int dt = 0; dt < 4; ++dt)                                           \
            _Pragma("unroll")                                                    \
            for (int qf = 0; qf < 4; ++qf)                                       \
                o[qf][dt] = __builtin_amdgcn_mfma_f32_16x16x32_f16(              \
                    vf[dt].h8, pf[qf].h8, o[qf][dt], 0, 0, 0);                   \
        __builtin_amdgcn_s_setprio(0);                                           \
        _Pragma("unroll")                                                        \
        for (int j = 0; j < 4; ++j)                                              \
            vf[j].i4 = *(const int4*)(tb_ + 2048 + j * 512 + loff);              \
    }

    // bodies 1..62 in odd/even pairs, then body 63 (its K/bias(64) prefetch
    // reads blob/bias tail pad -- dead values)
#pragma unroll 1
    for (int kp = 1; kp < KIT - 1; kp += 2) {
        BODY(kp, stB, stA)
        BODY(kp + 1, stA, stB)
    }
    BODY(KIT - 1, stB, stA)
#undef BODY

    // ---- epilogue: SM(63) from stB, PV(63) ----
#pragma unroll
    for (int kt = 0; kt < 2; ++kt)
#pragma unroll
        for (int qf = 0; qf < 4; ++qf) {
            float p0 = EXP2(stB[kt][qf][0]), p1 = EXP2(stB[kt][qf][1]);
            float p2 = EXP2(stB[kt][qf][2]), p3 = EXP2(stB[kt][qf][3]);
            lsum[qf] += (p0 + p1) + (p2 + p3);
            pf[qf].w[kt * 2]     = packh2(p0, p1);
            pf[qf].w[kt * 2 + 1] = packh2(p2, p3);
        }
    __builtin_amdgcn_s_setprio(1);
#pragma unroll
    for (int dt = 0; dt < 4; ++dt)
#pragma unroll
        for (int qf = 0; qf < 4; ++qf)
            o[qf][dt] = __builtin_amdgcn_mfma_f32_16x16x32_f16(vf[dt].h8, pf[qf].h8, o[qf][dt], 0, 0, 0);
    __builtin_amdgcn_s_setprio(0);

    // ---- finalize l ----
#pragma unroll
    for (int qf = 0; qf < 4; ++qf) {
        lsum[qf] += __shfl_xor(lsum[qf], 16, 64);
        lsum[qf] += __shfl_xor(lsum[qf], 32, 64);
    }

    // ---- split-K merge: partials add linearly (fixed max). 3 stages. ----
    float* MO = (float*)smem;              // [64][68]
    float* ML = (float*)(smem + 17408);    // [64]
#pragma unroll 1
    for (int src = 1; src < 4; ++src) {
        __syncthreads();
        if (kq == src) {
#pragma unroll
            for (int qf = 0; qf < 4; ++qf) {
                const int row = qf * 16 + low;
#pragma unroll
                for (int dt = 0; dt < 4; ++dt)
                    *(f32x4*)&MO[row * 68 + dt * 16 + h * 4] = o[qf][dt];
                if (h == 0) ML[row] = lsum[qf];
            }
        }
        __syncthreads();
        if (kq == 0) {
#pragma unroll
            for (int qf = 0; qf < 4; ++qf) {
                const int row = qf * 16 + low;
#pragma unroll
                for (int dt = 0; dt < 4; ++dt) {
                    f32x4 a = *(const f32x4*)&MO[row * 68 + dt * 16 + h * 4];
#pragma unroll
                    for (int jj = 0; jj < 4; ++jj) o[qf][dt][jj] += a[jj];
                }
                lsum[qf] += ML[row];
            }
        }
    }

    if (kq == 0) {
#pragma unroll
        for (int qf = 0; qf < 4; ++qf) {
            const float inv = 1.f / lsum[qf];
            float* orow = Out + ((size_t)(batch * S_LEN + q0 + qf * 16 + low)) * DHEAD;
#pragma unroll
            for (int dt = 0; dt < 4; ++dt) {
                f32x4 r;
#pragma unroll
                for (int jj = 0; jj < 4; ++jj) r[jj] = o[qf][dt][jj] * inv;
                *(f32x4*)(orow + dt * 16 + h * 4) = r;
            }
        }
    }
}

// ---------------------------------------------------------------------------
extern "C" void kernel_launch(void* const* d_in, const int* in_sizes, int n_in,
                              void* d_out, int out_size, void* d_ws, size_t ws_size,
                              hipStream_t stream) {
    const float* Q  = (const float*)d_in[0];
    const float* K  = (const float*)d_in[1];
    const float* V  = (const float*)d_in[2];
    const float* cr = (const float*)d_in[3];
    const float* ci = (const float*)d_in[4];
    const float* sc = (const float*)d_in[5];
    float* out = (float*)d_out;

    char* ws = (char*)d_ws;
    float* bias2 = (float*)ws;                   // 32 KB + 256 B tail pad  [0, 33024)
    u16*   blob  = (u16*)(ws + 33024);           // 8 MB + 8 KB tail pad

    prep_kernel<<<dim3(1056), dim3(256), 0, stream>>>(K, V, cr, ci, sc, blob, bias2);
    flash_kernel<<<dim3(512), dim3(256), 0, stream>>>(Q, blob, bias2, out);
}

// Round 9
// 148.751 us; speedup vs baseline: 1.6452x; 1.6452x over previous
//
#include <hip/hip_runtime.h>
#include <math.h>

#define S_LEN 8192
#define DHEAD 64
#define NBATCH 4
#define BK 32
#define KIT 64            // 2048 keys per kq-quarter / BK

typedef unsigned short u16;
typedef unsigned int u32;
typedef __attribute__((ext_vector_type(8))) _Float16 half8;
typedef __attribute__((ext_vector_type(2))) __fp16 fp16x2;
typedef __attribute__((ext_vector_type(4))) float f32x4;

union HU8 { int4 i4; half8 h8; u32 w[4]; };
union H2U { fp16x2 h2; u32 w; };
union HU  { _Float16 h; u16 u; };

#if __has_builtin(__builtin_amdgcn_exp2f)
#define EXP2(x) __builtin_amdgcn_exp2f(x)
#else
#define EXP2(x) exp2f(x)
#endif

// float -> f16 RNE
__device__ __forceinline__ u16 f2h(float f) {
    HU x; x.h = (_Float16)f; return x.u;
}
// two floats -> packed f16x2, single v_cvt_pkrtz_f16_f32
__device__ __forceinline__ u32 packh2(float a, float b) {
    H2U x; x.h2 = __builtin_amdgcn_cvt_pkrtz(a, b); return x.w;
}

// ---------------------------------------------------------------------------
// Prep: blocks [0,1024) pack K and V (both f16) of one 32-key tile
// (b = bid>>8, t = bid&255) into MFMA-fragment order:
//   blob[b][t] (8 KB) = K chunks j=0..3 (j=kt*2+ds) then V chunks dt=0..3,
//   chunk = 64 lanes x 16 B, exact flash lane order:
//     K: lane(low,h) -> K[b][t*32 + 8*(low>>2)+4*kt+(low&3)][ds*32+h*8+0..7]
//     V: lane(low,h) -> V[b][t*32 + h*8 + 0..7][dt*16+low]
// Blocks [1024,1056): Julia bias in f64 (matches numpy), fixed max M=20
// folded: bias2[k] = log(exp(et*scale)+1e-8)*log2e - 20.
// ---------------------------------------------------------------------------
__global__ void prep_kernel(const float* __restrict__ K, const float* __restrict__ V,
                            const float* crp, const float* cip, const float* scp,
                            u16* __restrict__ blob, float* __restrict__ bias2) {
    int bid = blockIdx.x, tid = threadIdx.x;
    if (bid < 1024) {
        int b = bid >> 8, t = bid & 255;
        __shared__ float Kt[32 * 64];
        __shared__ float Vt[32 * 65];          // padded rows: conflict-free col reads
        int row = tid >> 3, c8 = (tid & 7) * 8;
        const float* ks = K + ((size_t)(b * S_LEN + t * 32 + row)) * 64 + c8;
        const float* vs = V + ((size_t)(b * S_LEN + t * 32 + row)) * 64 + c8;
        float4 ka = *(const float4*)ks, kb4 = *(const float4*)(ks + 4);
        float4 va = *(const float4*)vs, vb4 = *(const float4*)(vs + 4);
        *(float4*)&Kt[row * 64 + c8] = ka;
        *(float4*)&Kt[row * 64 + c8 + 4] = kb4;
        float* vr = &Vt[row * 65 + c8];
        vr[0] = va.x; vr[1] = va.y; vr[2] = va.z; vr[3] = va.w;
        vr[4] = vb4.x; vr[5] = vb4.y; vr[6] = vb4.z; vr[7] = vb4.w;
        __syncthreads();

        int j = tid >> 6, lane = tid & 63, low = lane & 15, h = lane >> 4;
        u16* tb = blob + ((size_t)(b * 256 + t)) * 4096;   // u16 elems (8 KB)
        {   // K chunk j = kt*2 + ds  (f16)
            int kt = j >> 1, ds = j & 1;
            int krow = 8 * (low >> 2) + 4 * kt + (low & 3);
            const float* src = &Kt[krow * 64 + ds * 32 + h * 8];
            u32 wds[4];
#pragma unroll
            for (int i = 0; i < 4; ++i)
                wds[i] = (u32)f2h(src[2 * i]) | ((u32)f2h(src[2 * i + 1]) << 16);
            *(int4*)(tb + j * 512 + lane * 8) = make_int4(wds[0], wds[1], wds[2], wds[3]);
        }
        {   // V chunk dt = j  (f16)
            int col = j * 16 + low;
            u32 wds[4];
#pragma unroll
            for (int i = 0; i < 4; ++i) {
                float a = Vt[(h * 8 + 2 * i) * 65 + col];
                float c = Vt[(h * 8 + 2 * i + 1) * 65 + col];
                wds[i] = (u32)f2h(a) | ((u32)f2h(c) << 16);
            }
            *(int4*)(tb + 2048 + j * 512 + lane * 8) = make_int4(wds[0], wds[1], wds[2], wds[3]);
        }
    } else {
#pragma clang fp contract(off)
        int i = (bid - 1024) * 256 + tid;
        double cr = (double)crp[0], ci = (double)cip[0], sc = (double)scp[0];
        double step = 4.0 / (double)(S_LEN - 1);
        double x = (i == S_LEN - 1) ? 2.0 : (-2.0 + step * (double)i);
        double zr = x, zi = 0.0, et = 1.0;
        bool esc = false;
        for (int it = 0; it < 64; ++it) {
            double nzr = zr * zr - zi * zi + cr;
            double nzi = 2.0 * zr * zi + ci;
            if (!esc) { zr = nzr; zi = nzi; }
            double m2 = zr * zr + zi * zi;
            if (!esc && m2 > 4.0) { et = (double)it / 64.0; esc = true; }
        }
        double bias = log(exp(et * sc) + 1e-8);
        bias2[i] = (float)(bias * 1.4426950408889634 - 20.0);
    }
}

// ---------------------------------------------------------------------------
// Flash: packed-fragment streaming, no LDS / no barriers in the main loop.
//   grid 512 (2 blocks/CU), block 256 = 4 waves = 4 kq; each wave covers the
//   block's 64 q-rows (4 q-frags) x its 2048-key quarter, BK=32, 64 iters.
//
//   FINE-GRAIN INTERLEAVE (this revision).  Mechanism identified R7/R8: a
//   wave issuing 16 back-to-back MFMAs is ISSUE-BLOCKED (in-order issue,
//   each 16x16x32 MFMA occupies the matrix pipe ~17 cyc) and cannot issue
//   its independent VALU; the 2 lockstepped waves/SIMD stall together, so
//   the pipes' busy times ADD (R7: 563 matrix + 633 VALU ~ 1400 cyc/iter).
//   R8's per-qf interleave was right in spirit but spilled (live-range
//   explosion past the 256-reg/wave budget -> 300 MB scratch writes).
//   This version interleaves at the finest grain, pressure-neutral:
//     QK(i): 16 MFMA -> st (single buffer: SM is same-iteration again)
//     issue K/bias(i+1)
//     16 x { 1 PV(i-1) MFMA (o[qf][dt] += V(i-1)*pfPrev[qf])
//            ; 2 exp2(st) + lsum + 1 pack -> pfCur }   // temps: 2 floats
//     issue V(i)
//   Each PV MFMA's ~17-cycle pipe occupancy is covered by its paired SM
//   quarter-step's ~20 VALU cycles -> one wave alone feeds both pipes.
//   SM(i) reads st written >=250 cyc earlier (covered).  pf double-buffered
//   (pfA/pfB, compile-time parity via odd/even bodies); st single-buffered:
//   net register demand BELOW R7 (no stB).  launch_bounds(256,2) -- the
//   only known-good occupancy setting (R2/R3/R6 spilled under tighter caps).
//
//   All operands f16; fixed-max softmax (M=20 folded into bias);
//   4-way split-K merged by plain adds through LDS at the end.
// ---------------------------------------------------------------------------
__global__ __launch_bounds__(256, 2)
void flash_kernel(const float* __restrict__ Q, const u16* __restrict__ blob,
                  const float* __restrict__ bias2, float* __restrict__ Out) {
    __shared__ __align__(16) char smem[17664];   // merge scratch only

    const int tid = threadIdx.x;
    const int l = tid & 63, low = l & 15, h = l >> 4;
    const int kq = __builtin_amdgcn_readfirstlane(tid >> 6);

    const int bid = blockIdx.x;
    const int batch = bid & 3;          // XCD-affinity: batch b on XCDs {b, b+4}
    const int qtile = bid >> 2;         // 0..127 (BQ = 64)
    const int q0 = qtile * 64;

    // ---- Q fragments (4 x 16 q-rows, f16), scale log2(e)/8 folded ----
    const float qscale = 0.18033688011112042f;
    half8 qfrag[4][2];
#pragma unroll
    for (int qf = 0; qf < 4; ++qf) {
        const float* qrow = Q + ((size_t)(batch * S_LEN + q0 + qf * 16 + low)) * DHEAD + h * 8;
#pragma unroll
        for (int ds = 0; ds < 2; ++ds) {
            f32x4 a = *(const f32x4*)(qrow + ds * 32);
            f32x4 b = *(const f32x4*)(qrow + ds * 32 + 4);
            HU8 u;
            u.w[0] = packh2(a[0] * qscale, a[1] * qscale);
            u.w[1] = packh2(a[2] * qscale, a[3] * qscale);
            u.w[2] = packh2(b[0] * qscale, b[1] * qscale);
            u.w[3] = packh2(b[2] * qscale, b[3] * qscale);
            qfrag[qf][ds] = u.h8;
        }
    }

    // wave-uniform stream base (SGPR) + single lane offset (VGPR)
    const u16* kvb = blob + ((size_t)(batch * 256 + kq * 64)) * 4096;
    const int loff = l * 8;                         // u16 elems (16 B/lane)
    const float* bbase = bias2 + kq * 2048;

    f32x4 o[4][4];
#pragma unroll
    for (int qf = 0; qf < 4; ++qf)
#pragma unroll
        for (int dt = 0; dt < 4; ++dt) o[qf][dt] = (f32x4){0, 0, 0, 0};
    float lsum[4] = {0.f, 0.f, 0.f, 0.f};

    HU8 kf[4];           // K buffer (compiler renames across WAR)
    f32x4 bvv[2];        // bias buffer
    HU8 vf[4];           // V buffer
    HU8 pfA[4];          // P frags, double-buffered: pf(i) = (i even) ? A : B
    HU8 pfB[4];
    f32x4 st[2][4];      // scores of tile i (single buffer)

    // ---- prologue: QK(0) -> st; issue K/bias(1); SM(0) -> pfA; V(0) ----
#pragma unroll
    for (int j = 0; j < 4; ++j) kf[j].i4 = *(const int4*)(kvb + j * 512 + loff);
    bvv[0] = *(const f32x4*)(bbase + h * 8);
    bvv[1] = *(const f32x4*)(bbase + h * 8 + 4);
#pragma unroll
    for (int kt = 0; kt < 2; ++kt) {
        const f32x4 binit = kt ? bvv[1] : bvv[0];
#pragma unroll
        for (int qf = 0; qf < 4; ++qf) {
            f32x4 a = __builtin_amdgcn_mfma_f32_16x16x32_f16(kf[kt * 2].h8, qfrag[qf][0], binit, 0, 0, 0);
            st[kt][qf] = __builtin_amdgcn_mfma_f32_16x16x32_f16(kf[kt * 2 + 1].h8, qfrag[qf][1], a, 0, 0, 0);
        }
    }
#pragma unroll
    for (int j = 0; j < 4; ++j) kf[j].i4 = *(const int4*)(kvb + 4096 + j * 512 + loff);
    bvv[0] = *(const f32x4*)(bbase + 32 + h * 8);
    bvv[1] = *(const f32x4*)(bbase + 32 + h * 8 + 4);
#pragma unroll
    for (int kt = 0; kt < 2; ++kt)
#pragma unroll
        for (int qf = 0; qf < 4; ++qf) {
            float p0 = EXP2(st[kt][qf][0]), p1 = EXP2(st[kt][qf][1]);
            float p2 = EXP2(st[kt][qf][2]), p3 = EXP2(st[kt][qf][3]);
            lsum[qf] += (p0 + p1) + (p2 + p3);
            pfA[qf].w[kt * 2]     = packh2(p0, p1);
            pfA[qf].w[kt * 2 + 1] = packh2(p2, p3);
        }
#pragma unroll
    for (int j = 0; j < 4; ++j) vf[j].i4 = *(const int4*)(kvb + 2048 + j * 512 + loff);

    // BODY(KI, PFP, PFC):
    //   QK(KI) -> st              (kf=K(KI), bvv=bias(KI))
    //   issue K/bias(KI+1)        (kf/bvv WAR -> compiler renames)
    //   16 x { PV(KI-1) MFMA step (vf=V(KI-1), PFP=pf(KI-1))
    //          ; SM(KI) quarter-step from st -> PFC }
    //   issue V(KI) -> vf
#define BODY(KI, PFP, PFC)                                                       \
    {                                                                            \
        const u16* tb_ = kvb + (size_t)(KI) * 4096;                              \
        const u16* tn_ = tb_ + 4096;                                             \
        _Pragma("unroll")                                                        \
        for (int kt = 0; kt < 2; ++kt) {                                         \
            const f32x4 binit = kt ? bvv[1] : bvv[0];                            \
            _Pragma("unroll")                                                    \
            for (int qf = 0; qf < 4; ++qf) {                                     \
                f32x4 a = __builtin_amdgcn_mfma_f32_16x16x32_f16(                \
                    kf[kt * 2].h8, qfrag[qf][0], binit, 0, 0, 0);                \
                st[kt][qf] = __builtin_amdgcn_mfma_f32_16x16x32_f16(             \
                    kf[kt * 2 + 1].h8, qfrag[qf][1], a, 0, 0, 0);                \
            }                                                                    \
        }                                                                        \
        _Pragma("unroll")                                                        \
        for (int j = 0; j < 4; ++j)                                              \
            kf[j].i4 = *(const int4*)(tn_ + j * 512 + loff);                     \
        const float* bpn_ = bbase + ((KI) + 1) * 32 + h * 8;                     \
        bvv[0] = *(const f32x4*)bpn_;                                            \
        bvv[1] = *(const f32x4*)(bpn_ + 4);                                      \
        _Pragma("unroll")                                                        \
        for (int s = 0; s < 16; ++s) {                                           \
            const int dt = s >> 2, qfp = s & 3;                                  \
            o[qfp][dt] = __builtin_amdgcn_mfma_f32_16x16x32_f16(                 \
                vf[dt].h8, PFP[qfp].h8, o[qfp][dt], 0, 0, 0);                    \
            const int kt = s >> 3, qfs = (s >> 1) & 3, pr = s & 1;               \
            float pa = EXP2(st[kt][qfs][2 * pr]);                                \
            float pb = EXP2(st[kt][qfs][2 * pr + 1]);                            \
            lsum[qfs] += pa + pb;                                                \
            PFC[qfs].w[kt * 2 + pr] = packh2(pa, pb);                            \
        }                                                                        \
        _Pragma("unroll")                                                        \
        for (int j = 0; j < 4; ++j)                                              \
            vf[j].i4 = *(const int4*)(tb_ + 2048 + j * 512 + loff);              \
    }

    // bodies 1..62 in odd/even pairs, then body 63 (its K/bias(64) prefetch
    // reads blob/bias tail pad -- dead values)
#pragma unroll 1
    for (int kp = 1; kp < KIT - 1; kp += 2) {
        BODY(kp, pfA, pfB)
        BODY(kp + 1, pfB, pfA)
    }
    BODY(KIT - 1, pfA, pfB)
#undef BODY

    // ---- epilogue: PV(63) with pfB, vf=V(63) ----
#pragma unroll
    for (int dt = 0; dt < 4; ++dt)
#pragma unroll
        for (int qf = 0; qf < 4; ++qf)
            o[qf][dt] = __builtin_amdgcn_mfma_f32_16x16x32_f16(vf[dt].h8, pfB[qf].h8, o[qf][dt], 0, 0, 0);

    // ---- finalize l ----
#pragma unroll
    for (int qf = 0; qf < 4; ++qf) {
        lsum[qf] += __shfl_xor(lsum[qf], 16, 64);
        lsum[qf] += __shfl_xor(lsum[qf], 32, 64);
    }

    // ---- split-K merge: partials add linearly (fixed max). 3 stages. ----
    float* MO = (float*)smem;              // [64][68]
    float* ML = (float*)(smem + 17408);    // [64]
#pragma unroll 1
    for (int src = 1; src < 4; ++src) {
        __syncthreads();
        if (kq == src) {
#pragma unroll
            for (int qf = 0; qf < 4; ++qf) {
                const int row = qf * 16 + low;
#pragma unroll
                for (int dt = 0; dt < 4; ++dt)
                    *(f32x4*)&MO[row * 68 + dt * 16 + h * 4] = o[qf][dt];
                if (h == 0) ML[row] = lsum[qf];
            }
        }
        __syncthreads();
        if (kq == 0) {
#pragma unroll
            for (int qf = 0; qf < 4; ++qf) {
                const int row = qf * 16 + low;
#pragma unroll
                for (int dt = 0; dt < 4; ++dt) {
                    f32x4 a = *(const f32x4*)&MO[row * 68 + dt * 16 + h * 4];
#pragma unroll
                    for (int jj = 0; jj < 4; ++jj) o[qf][dt][jj] += a[jj];
                }
                lsum[qf] += ML[row];
            }
        }
    }

    if (kq == 0) {
#pragma unroll
        for (int qf = 0; qf < 4; ++qf) {
            const float inv = 1.f / lsum[qf];
            float* orow = Out + ((size_t)(batch * S_LEN + q0 + qf * 16 + low)) * DHEAD;
#pragma unroll
            for (int dt = 0; dt < 4; ++dt) {
                f32x4 r;
#pragma unroll
                for (int jj = 0; jj < 4; ++jj) r[jj] = o[qf][dt][jj] * inv;
                *(f32x4*)(orow + dt * 16 + h * 4) = r;
            }
        }
    }
}

// ---------------------------------------------------------------------------
extern "C" void kernel_launch(void* const* d_in, const int* in_sizes, int n_in,
                              void* d_out, int out_size, void* d_ws, size_t ws_size,
                              hipStream_t stream) {
    const float* Q  = (const float*)d_in[0];
    const float* K  = (const float*)d_in[1];
    const float* V  = (const float*)d_in[2];
    const float* cr = (const float*)d_in[3];
    const float* ci = (const float*)d_in[4];
    const float* sc = (const float*)d_in[5];
    float* out = (float*)d_out;

    char* ws = (char*)d_ws;
    float* bias2 = (float*)ws;                   // 32 KB + 256 B tail pad  [0, 33024)
    u16*   blob  = (u16*)(ws + 33024);           // 8 MB + 8 KB tail pad

    prep_kernel<<<dim3(1056), dim3(256), 0, stream>>>(K, V, cr, ci, sc, blob, bias2);
    flash_kernel<<<dim3(512), dim3(256), 0, stream>>>(Q, blob, bias2, out);
}